// Round 4
// baseline (423.848 us; speedup 1.0000x reference)
//
#include <hip/hip_runtime.h>
#include <stdint.h>

#define BATCH   16
#define NPTS    8192
#define NGRP    512
#define MSEL    32
#define THREADS 256
#define PPT     (NPTS / THREADS)   // 32 points per thread

// Map fp32 bits to monotonically increasing uint32 (ascending float order).
__device__ __forceinline__ uint32_t sortable(float f) {
    uint32_t b = __float_as_uint(f);
    return b ^ (uint32_t)(((int32_t)b >> 31) | (int32_t)0x80000000);
}

extern "C" __global__ void __launch_bounds__(THREADS)
knn_group_kernel(const float* __restrict__ xyz,
                 const float* __restrict__ cen,
                 float* __restrict__ out)
{
    const int bg = blockIdx.x;            // 0 .. BATCH*NGRP-1
    const int b  = bg >> 9;               // / NGRP
    const float* xb = xyz + (size_t)b * NPTS * 3;

    const float c0 = cen[(size_t)bg * 3 + 0];
    const float c1 = cen[(size_t)bg * 3 + 1];
    const float c2 = cen[(size_t)bg * 3 + 2];
    // c^2: np.sum(c*c) — separate ufuncs, forward adds, no FMA
    const float csq = __fadd_rn(__fadd_rn(__fmul_rn(c0, c0), __fmul_rn(c1, c1)),
                                __fmul_rn(c2, c2));

    const int tid = threadIdx.x;

    // Per-thread keys in registers; all accesses static-indexed (unrolled).
    unsigned long long key[PPT];
#pragma unroll
    for (int j = 0; j < PPT; ++j) {
        const int n = tid + j * THREADS;  // coalesced across lanes
        const float x0 = xb[n * 3 + 0];
        const float x1 = xb[n * 3 + 1];
        const float x2 = xb[n * 3 + 2];
        // x^2: forward adds, no FMA (ufunc path)
        const float xsq = __fadd_rn(__fadd_rn(__fmul_rn(x0, x0), __fmul_rn(x1, x1)),
                                    __fmul_rn(x2, x2));
        // BLAS/XLA sgemm K=3 microkernel: k-ascending FMA accumulation
        //   acc = c0*x0; acc = fma(c1,x1,acc); acc = fma(c2,x2,acc)
        const float dot = __fmaf_rn(c2, x2,
                          __fmaf_rn(c1, x1,
                          __fmul_rn(c0, x0)));
        // dist = (c2 - 2.0*cx) + x2, separate rounded ufunc ops (2*dot exact)
        const float d = __fadd_rn(__fsub_rn(csq, __fmul_rn(2.0f, dot)), xsq);
        key[j] = ((unsigned long long)sortable(d) << 32) | (unsigned)n;
    }

    // Cached per-thread minimum
    unsigned long long lmin = key[0];
#pragma unroll
    for (int j = 1; j < PPT; ++j) lmin = (key[j] < lmin) ? key[j] : lmin;

    __shared__ unsigned long long wred[THREADS / 64];
    __shared__ unsigned long long bc;

    for (int r = 0; r < MSEL; ++r) {
        // wave-level u64 min reduce (primary: fp32 dist bits, secondary: index)
        unsigned long long v = lmin;
#pragma unroll
        for (int off = 32; off >= 1; off >>= 1) {
            unsigned long long o = __shfl_xor(v, off, 64);
            v = (o < v) ? o : v;
        }
        if ((tid & 63) == 0) wred[tid >> 6] = v;
        __syncthreads();
        if (tid == 0) {
            unsigned long long m = wred[0];
#pragma unroll
            for (int w = 1; w < THREADS / 64; ++w) m = (wred[w] < m) ? wred[w] : m;
            bc = m;
            // rank-r output: exact fp32 gather-subtract
            const int n = (int)(m & 0xFFFFFFFFull);
            float* op = out + ((size_t)bg * MSEL + r) * 3;
            op[0] = __fsub_rn(xb[n * 3 + 0], c0);
            op[1] = __fsub_rn(xb[n * 3 + 1], c1);
            op[2] = __fsub_rn(xb[n * 3 + 2], c2);
        }
        __syncthreads();
        const unsigned long long w = bc;
        // Winner invalidates its slot and rescans (static-indexed, unrolled).
        if (lmin == w) {
            unsigned long long nm = ~0ull;
#pragma unroll
            for (int j = 0; j < PPT; ++j) {
                if (key[j] == w) key[j] = ~0ull;
                nm = (key[j] < nm) ? key[j] : nm;
            }
            lmin = nm;
        }
        // bc is rewritten only after the next round's first __syncthreads(); safe.
    }
}

extern "C" void kernel_launch(void* const* d_in, const int* in_sizes, int n_in,
                              void* d_out, int out_size, void* d_ws, size_t ws_size,
                              hipStream_t stream) {
    const float* xyz = (const float*)d_in[0];   // (16, 8192, 3) fp32
    const float* cen = (const float*)d_in[1];   // (16, 512, 3) fp32
    float* out = (float*)d_out;                 // (16, 512, 32, 3) fp32

    knn_group_kernel<<<dim3(BATCH * NGRP), dim3(THREADS), 0, stream>>>(xyz, cen, out);
}